// Round 2
// baseline (28264.868 us; speedup 1.0000x reference)
//
#include <hip/hip_runtime.h>
#include <hip/hip_bf16.h>
#include <stdint.h>

#define T_LEN 16384
#define HDIM 512
#define G4 2048
#define CLAMP_MAXV 49688.0f

// workspace layout (bytes)
#define XG_OFF    0ull
#define HS_OFF    134217728ull   // 16384*2048*4
#define INTER_OFF 167772160ull   // + 16384*512*4   (inter written AFTER scan;
                                 //  hfast/hslow/bsum overlay its head before that)
#define HFAST_OFF 167772160ull
#define HSLOW_OFF 167780352ull   // +8192
#define BSUM_OFF  167788544ull   // +8192
#define WS_NEED   176177152ull   // INTER_OFF + 16384*128*4

// ---------------------------------------------------------------------------
// init: zero both h-broadcast buffers (tags incl.), fold biases
// ---------------------------------------------------------------------------
__global__ __launch_bounds__(256) void init_k(uint64_t* __restrict__ hfast,
                                              uint64_t* __restrict__ hslow,
                                              const float* __restrict__ b_ih,
                                              const float* __restrict__ b_hh,
                                              float* __restrict__ bsum) {
    int i = blockIdx.x * 256 + threadIdx.x;   // grid 8x256 -> i in [0,2048)
    if (i < 1024) { hfast[i] = 0ull; hslow[i] = 0ull; }  // tag 0 = h_{-1} ready
    bsum[i] = b_ih[i] + b_hh[i];
}

// ---------------------------------------------------------------------------
// C[M,N] = A[M,K] @ B[N,K]^T + bias[N]   (both operands K-contiguous)
// 64x64 tile, 256 threads, 4x4 micro-tile, K-tile 16, LDS transposed + padded
// ---------------------------------------------------------------------------
__global__ __launch_bounds__(256) void gemm_abt(const float* __restrict__ A,
                                                const float* __restrict__ B,
                                                const float* __restrict__ bias,
                                                float* __restrict__ C,
                                                int N, int K) {
    __shared__ float As[16][68];
    __shared__ float Bs[16][68];
    const int tid = threadIdx.x;
    const int bm = blockIdx.x << 6, bn = blockIdx.y << 6;
    const int tx = tid & 15, ty = tid >> 4;
    const int lr = tid >> 2, lk = (tid & 3) << 2;
    float acc[4][4] = {};
    const float* Ap = A + (size_t)(bm + lr) * K + lk;
    const float* Bp = B + (size_t)(bn + lr) * K + lk;
    for (int kt = 0; kt < K; kt += 16) {
        float4 av = *(const float4*)(Ap + kt);
        float4 bv = *(const float4*)(Bp + kt);
        __syncthreads();
        As[lk + 0][lr] = av.x; As[lk + 1][lr] = av.y;
        As[lk + 2][lr] = av.z; As[lk + 3][lr] = av.w;
        Bs[lk + 0][lr] = bv.x; Bs[lk + 1][lr] = bv.y;
        Bs[lk + 2][lr] = bv.z; Bs[lk + 3][lr] = bv.w;
        __syncthreads();
#pragma unroll
        for (int kk = 0; kk < 16; ++kk) {
            float4 a4 = *(const float4*)&As[kk][ty << 2];
            float4 b4 = *(const float4*)&Bs[kk][tx << 2];
            acc[0][0] += a4.x * b4.x; acc[0][1] += a4.x * b4.y;
            acc[0][2] += a4.x * b4.z; acc[0][3] += a4.x * b4.w;
            acc[1][0] += a4.y * b4.x; acc[1][1] += a4.y * b4.y;
            acc[1][2] += a4.y * b4.z; acc[1][3] += a4.y * b4.w;
            acc[2][0] += a4.z * b4.x; acc[2][1] += a4.z * b4.y;
            acc[2][2] += a4.z * b4.z; acc[2][3] += a4.z * b4.w;
            acc[3][0] += a4.w * b4.x; acc[3][1] += a4.w * b4.y;
            acc[3][2] += a4.w * b4.z; acc[3][3] += a4.w * b4.w;
        }
    }
    const int col = bn + (tx << 2);
    float4 bv4 = *(const float4*)&bias[col];
#pragma unroll
    for (int i = 0; i < 4; ++i) {
        int row = bm + (ty << 2) + i;
        float4 o;
        o.x = acc[i][0] + bv4.x; o.y = acc[i][1] + bv4.y;
        o.z = acc[i][2] + bv4.z; o.w = acc[i][3] + bv4.w;
        *(float4*)&C[(size_t)row * N + col] = o;
    }
}

// ---------------------------------------------------------------------------
// Persistent LSTM scan, single-XCD fast path.
// Launch 256 blocks x 512; only blockIdx%8==0 work (round-robin dispatch puts
// all 32 workers on XCD 0, sharing one L2). Publish = plain write-through
// store into hfast (L2-coherent within the XCD) + agent-scope atomic mirror
// in hslow (LLC) as the correctness net; readers poll hfast with volatile
// (sc0) loads and latch to the hslow path if the fast path never validates.
// 8-byte self-validating atoms: (uint32 tag<<32 | fp32 h).
// W_hh slice pinned in VGPRs (64 floats/thread) via asm register barrier.
// One barrier per step: each wave polls exactly the h-segment its own matvec
// reads (wave-private LDS), part[] is parity double-buffered.
// ---------------------------------------------------------------------------
__global__ __launch_bounds__(512, 1) void lstm_scan(const float* __restrict__ W_hh,
                                                    const float* __restrict__ xg,
                                                    float* __restrict__ hs,
                                                    uint64_t* __restrict__ hfast,
                                                    uint64_t* __restrict__ hslow) {
    if (blockIdx.x & 7) return;       // workers: 0,8,...,248 -> one XCD (heuristic)
    const int j = blockIdx.x >> 3;    // 0..31
    __shared__ float h_lds[512];
    __shared__ float part[2][512];
    const int tid = threadIdx.x;
    const int wv = tid >> 6;          // wave 0..7 = k segment
    const int lane = tid & 63;
    // global gate row: 512*gate + 16*j + u   (gate = lane>>4, u = lane&15)
    const int rowg = ((lane >> 4) << 9) | (j << 4) | (lane & 15);

    float4 w4[16];
    {
        const float4* wp = (const float4*)(W_hh + (size_t)rowg * HDIM + (wv << 6));
#pragma unroll
        for (int q = 0; q < 16; ++q) w4[q] = wp[q];
#pragma unroll
        for (int q = 0; q < 16; ++q)
            asm volatile("" : "+v"(w4[q].x), "+v"(w4[q].y),
                              "+v"(w4[q].z), "+v"(w4[q].w));
    }

    int use_slow = 0;
    float c_reg = 0.f;                // valid on wave 0, lanes 0..15
    for (int t = 0; t < T_LEN; ++t) {
        const int par = t & 1;
        // prefetch this step's x-gate contribution (hidden behind the spin)
        float xgv = 0.f;
        if (wv == 0) xgv = __builtin_nontemporal_load(&xg[(size_t)t * G4 + rowg]);

        // ---- acquire my h element for step t ----
        uint64_t u = 0;
        {
            const volatile uint64_t* fsrc =
                (const volatile uint64_t*)(hfast + (par << 9) + tid);
            if (!use_slow) {
                int tries = 0;
                for (;;) {
                    u = *fsrc;
                    if ((uint32_t)(u >> 32) == (uint32_t)t) break;
                    if (++tries >= 4096) { use_slow = 1; break; }
                }
            }
            if (use_slow) {
                uint64_t* ssrc = hslow + (par << 9) + tid;
                int g = 0;
                do {
                    u = __hip_atomic_load(ssrc, __ATOMIC_RELAXED,
                                          __HIP_MEMORY_SCOPE_AGENT);
                } while ((uint32_t)(u >> 32) != (uint32_t)t && ++g < (1 << 22));
            }
        }
        h_lds[tid] = __uint_as_float((uint32_t)u);
        // wave-private segment: ds_write visible to own wave after lgkm drain
        asm volatile("s_waitcnt lgkmcnt(0)" ::: "memory");

        // matvec partial over my 64-k segment (LDS broadcast reads)
        float ac0 = 0.f, ac1 = 0.f, ac2 = 0.f, ac3 = 0.f;
        const float* hp = h_lds + (wv << 6);
#pragma unroll
        for (int q = 0; q < 16; q += 4) {
            float4 h0 = *(const float4*)(hp + (q << 2));
            float4 h1 = *(const float4*)(hp + ((q + 1) << 2));
            float4 h2 = *(const float4*)(hp + ((q + 2) << 2));
            float4 h3 = *(const float4*)(hp + ((q + 3) << 2));
            ac0 += w4[q].x * h0.x + w4[q].y * h0.y + w4[q].z * h0.z + w4[q].w * h0.w;
            ac1 += w4[q + 1].x * h1.x + w4[q + 1].y * h1.y + w4[q + 1].z * h1.z + w4[q + 1].w * h1.w;
            ac2 += w4[q + 2].x * h2.x + w4[q + 2].y * h2.y + w4[q + 2].z * h2.z + w4[q + 2].w * h2.w;
            ac3 += w4[q + 3].x * h3.x + w4[q + 3].y * h3.y + w4[q + 3].z * h3.z + w4[q + 3].w * h3.w;
        }
        part[par][tid] = (ac0 + ac1) + (ac2 + ac3);
        __syncthreads();

        if (wv == 0) {
            float g = xgv;
#pragma unroll
            for (int ww = 0; ww < 8; ++ww) g += part[par][(ww << 6) | lane];
            // rows 0..15 i(sig), 16..31 f(sig), 32..47 g(tanh), 48..63 o(sig)
            bool isg = (lane >= 32) && (lane < 48);
            float y = isg ? (g + g) : g;
            float s = 1.f / (1.f + __expf(-y));
            float a = isg ? (s + s - 1.f) : s;   // tanh(x) = 2*sig(2x)-1
            float fa = __shfl_down(a, 16);
            float ga = __shfl_down(a, 32);
            float oa = __shfl_down(a, 48);
            if (lane < 16) {
                c_reg = fa * c_reg + a * ga;
                float e2 = __expf(-2.f * c_reg);
                float hv = oa * (2.f / (1.f + e2) - 1.f);   // o * tanh(c)
                __builtin_nontemporal_store(hv, &hs[(size_t)t * HDIM + (j << 4) + lane]);
                uint64_t pu = ((uint64_t)(uint32_t)(t + 1) << 32) |
                              (uint64_t)__float_as_uint(hv);
                const int dst = (((t + 1) & 1) << 9) + (j << 4) + lane;
                *(volatile uint64_t*)(hfast + dst) = pu;           // L2 fast path
                __hip_atomic_store(hslow + dst, pu, __ATOMIC_RELAXED,
                                   __HIP_MEMORY_SCOPE_AGENT);      // LLC net
            }
        }
        // part[] is parity double-buffered; h_lds is wave-private -> the one
        // barrier above is the only cross-wave sync needed per step.
    }
}

// ---------------------------------------------------------------------------
// heads: per block, 64 t-rows. inter tile + transposed head weights in LDS.
// action = clip(inter@fc1^T + b1), obj = clip(inter@fc2^T + b2)
// ---------------------------------------------------------------------------
__global__ __launch_bounds__(256) void heads_k(const float* __restrict__ inter,
                                               const float* __restrict__ fc1w,
                                               const float* __restrict__ fc1b,
                                               const float* __restrict__ fc2w,
                                               const float* __restrict__ fc2b,
                                               float* __restrict__ out) {
    __shared__ float it[64][128];   // 32 KB
    __shared__ float wt[128][56];   // 28 KB, transposed: [k][neuron]
    __shared__ float bl[56];
    const int tid = threadIdx.x;
    const int t0 = blockIdx.x << 6;
    for (int q = tid; q < 64 * 32; q += 256) {
        int r = q >> 5, c4 = q & 31;
        *(float4*)&it[r][c4 << 2] =
            *(const float4*)&inter[(size_t)(t0 + r) * 128 + (c4 << 2)];
    }
    for (int q = tid; q < 53 * 32; q += 256) {
        int r = q >> 5, c4 = q & 31;
        float4 v = (r < 16) ? ((const float4*)&fc1w[r * 128])[c4]
                            : ((const float4*)&fc2w[(r - 16) * 128])[c4];
        int k = c4 << 2;
        wt[k + 0][r] = v.x; wt[k + 1][r] = v.y; wt[k + 2][r] = v.z; wt[k + 3][r] = v.w;
    }
    if (tid < 53) bl[tid] = (tid < 16) ? fc1b[tid] : fc2b[tid - 16];
    __syncthreads();
    const int c = tid & 63, rg = tid >> 6;
    if (c < 53) {
        float b = bl[c];
        for (int rr = 0; rr < 16; ++rr) {
            int r = (rg << 4) + rr;
            float acc = b;
#pragma unroll 8
            for (int k = 0; k < 128; k += 4) {
                float4 iv = *(const float4*)&it[r][k];
                acc += iv.x * wt[k][c] + iv.y * wt[k + 1][c] +
                       iv.z * wt[k + 2][c] + iv.w * wt[k + 3][c];
            }
            acc = fminf(fmaxf(acc, 0.f), CLAMP_MAXV);
            int t = t0 + r;
            if (c < 16) out[(size_t)t * 16 + c] = acc;
            else        out[262144 + (size_t)t * 37 + (c - 16)] = acc;
        }
    }
}

// ---------------------------------------------------------------------------
extern "C" void kernel_launch(void* const* d_in, const int* in_sizes, int n_in,
                              void* d_out, int out_size, void* d_ws, size_t ws_size,
                              hipStream_t stream) {
    const float* x     = (const float*)d_in[0];
    const float* W_ih  = (const float*)d_in[1];
    const float* W_hh  = (const float*)d_in[2];
    const float* b_ih  = (const float*)d_in[3];
    const float* b_hh  = (const float*)d_in[4];
    const float* fc_w  = (const float*)d_in[5];
    const float* fc_b  = (const float*)d_in[6];
    const float* fc1_w = (const float*)d_in[7];
    const float* fc1_b = (const float*)d_in[8];
    const float* fc2_w = (const float*)d_in[9];
    const float* fc2_b = (const float*)d_in[10];

    if (ws_size < WS_NEED) return;   // visible failure rather than corruption

    char* ws = (char*)d_ws;
    float*    xg    = (float*)(ws + XG_OFF);
    float*    hs    = (float*)(ws + HS_OFF);
    float*    inter = (float*)(ws + INTER_OFF);
    uint64_t* hfast = (uint64_t*)(ws + HFAST_OFF);
    uint64_t* hslow = (uint64_t*)(ws + HSLOW_OFF);
    float*    bsum  = (float*)(ws + BSUM_OFF);
    float*    out   = (float*)d_out;

    hipLaunchKernelGGL(init_k, dim3(8), dim3(256), 0, stream,
                       hfast, hslow, b_ih, b_hh, bsum);
    // x_gates = x @ W_ih^T + (b_ih + b_hh)   [16384 x 2048]
    hipLaunchKernelGGL(gemm_abt, dim3(256, 32), dim3(256), 0, stream,
                       x, W_ih, bsum, xg, 2048, 512);
    // sequential scan -> hs [16384 x 512]
    hipLaunchKernelGGL(lstm_scan, dim3(256), dim3(512), 0, stream,
                       W_hh, xg, hs, hfast, hslow);
    // inter = hs @ fc_w^T + fc_b   [16384 x 128]
    hipLaunchKernelGGL(gemm_abt, dim3(256, 2), dim3(256), 0, stream,
                       hs, fc_w, fc_b, inter, 128, 512);
    // heads -> d_out
    hipLaunchKernelGGL(heads_k, dim3(256), dim3(256), 0, stream,
                       inter, fc1_w, fc1_b, fc2_w, fc2_b, out);
}